// Round 2
// 1018.452 us; speedup vs baseline: 1.0391x; 1.0391x over previous
//
#include <hip/hip_runtime.h>

typedef __attribute__((ext_vector_type(8))) short short8;
typedef __attribute__((ext_vector_type(8))) unsigned short ushortx8;
typedef __attribute__((ext_vector_type(4))) unsigned short ushortx4;
typedef __attribute__((ext_vector_type(4))) float floatx4;

#define SCALE_F 0.08838834764831845f  // 128^-0.5

__device__ __forceinline__ float b2f(unsigned short u) {
  union { unsigned int u; float f; } c; c.u = ((unsigned int)u) << 16; return c.f;
}
__device__ __forceinline__ unsigned short f2b(float f) {
  union { float f; unsigned int u; } c; c.f = f;
  unsigned int u = c.u;
  u += 0x7fffu + ((u >> 16) & 1u);  // RNE; inputs never NaN
  return (unsigned short)(u >> 16);
}

#define GLD_LDS16(g, l)                                              \
  __builtin_amdgcn_global_load_lds(                                  \
      (const __attribute__((address_space(1))) void*)(g),            \
      (__attribute__((address_space(3))) void*)(l), 16, 0, 0)

// ---------------------------------------------------------------------------
// cast fp32 -> bf16 (vectorized x4)
// ---------------------------------------------------------------------------
__global__ __launch_bounds__(256) void cast_bf16_kernel(
    const float* __restrict__ x, unsigned short* __restrict__ y, int n) {
  int i = (blockIdx.x * 256 + threadIdx.x) * 4;
  if (i >= n) return;
  float4 v = *(const float4*)(x + i);
  ushortx4 o;
  o[0] = f2b(v.x); o[1] = f2b(v.y); o[2] = f2b(v.z); o[3] = f2b(v.w);
  *(ushortx4*)(y + i) = o;
}

// ---------------------------------------------------------------------------
// split2: x[R][1024] f32 -> y[R][2048] bf16 = [hi | lo]  (projection A')
// ---------------------------------------------------------------------------
__global__ __launch_bounds__(256) void split2_kernel(
    const float* __restrict__ x, unsigned short* __restrict__ y) {
  int idx = blockIdx.x * 256 + threadIdx.x;
  int row = idx >> 8;
  int c4 = (idx & 255) * 4;
  float4 v = *(const float4*)(x + (size_t)row * 1024 + c4);
  ushortx4 hi, lo;
  hi[0] = f2b(v.x); lo[0] = f2b(v.x - b2f(hi[0]));
  hi[1] = f2b(v.y); lo[1] = f2b(v.y - b2f(hi[1]));
  hi[2] = f2b(v.z); lo[2] = f2b(v.z - b2f(hi[2]));
  hi[3] = f2b(v.w); lo[3] = f2b(v.w - b2f(hi[3]));
  unsigned short* yr = y + (size_t)row * 2048;
  *(ushortx4*)(yr + c4) = hi;
  *(ushortx4*)(yr + 1024 + c4) = lo;
}

// ---------------------------------------------------------------------------
// transpose+split W_qk[1024][2048] f32 -> y[2048][2048] bf16 = [hi | hi]
// pairs with A'=[hi|lo]: sum = hi_a*hi_b + lo_a*hi_b  (hi_a*lo_b omitted)
// ---------------------------------------------------------------------------
__global__ __launch_bounds__(256) void transpose_split_qk(
    const float* __restrict__ W, unsigned short* __restrict__ y) {
  __shared__ float tile[32][33];
  int t = threadIdx.x, tx = t & 31, ty = t >> 5;
  int n0 = blockIdx.x * 32, k0 = blockIdx.y * 32;
  for (int rr = ty; rr < 32; rr += 8)
    tile[rr][tx] = W[(size_t)(k0 + rr) * 2048 + n0 + tx];
  __syncthreads();
  for (int rr = ty; rr < 32; rr += 8) {
    float v = tile[tx][rr];
    unsigned short hi = f2b(v);
    unsigned short* yr = y + (size_t)(n0 + rr) * 2048;
    yr[k0 + tx] = hi;
    yr[1024 + k0 + tx] = hi;
  }
}

// ---------------------------------------------------------------------------
// generic 32x32 tiled transpose, batched over (b,h) from p=pstart+z
// MODE 0: f32->bf16   2: bf16->bf16
// ---------------------------------------------------------------------------
template<int MODE>
__global__ __launch_bounds__(256) void transpose_any(
    const void* __restrict__ inv, void* __restrict__ outv,
    int R, int C, int ldin, int ldout,
    long sIb, long sIh, long sOb, long sOh, int pstart) {
  int z = blockIdx.z, p = pstart + z, b = p >> 3, h = p & 7;
  size_t ioff = (size_t)(sIb * b + sIh * h);
  size_t ooff = (size_t)(sOb * b + sOh * h);
  __shared__ float tile[32][33];
  int t = threadIdx.x, tx = t & 31, ty = t >> 5;
  int c0 = blockIdx.x * 32, r0 = blockIdx.y * 32;
  for (int rr = ty; rr < 32; rr += 8) {
    size_t idx = ioff + (size_t)(r0 + rr) * ldin + (c0 + tx);
    tile[rr][tx] = (MODE == 2) ? b2f(((const unsigned short*)inv)[idx])
                               : ((const float*)inv)[idx];
  }
  __syncthreads();
  for (int rr = ty; rr < 32; rr += 8) {
    size_t idx = ooff + (size_t)(c0 + rr) * ldout + (r0 + tx);
    ((unsigned short*)outv)[idx] = f2b(tile[tx][rr]);
  }
}

// ---------------------------------------------------------------------------
// m97-style bf16 MFMA GEMM: C[M][N] = A[M][K] @ BT[N][K]^T
// 128x128 tile, BK=32, 256 thr = 4 waves, wave = 64x64 quadrant = 4x4 MFMA
// ---------------------------------------------------------------------------
template<int OUT_BF16, int ADD_BIAS>
__global__ __launch_bounds__(256) void gemm128(
    const unsigned short* __restrict__ A, const unsigned short* __restrict__ BT,
    void* __restrict__ Cv, const float* __restrict__ bias,
    int K, int lda, int ldb, int ldc,
    long sAz, long sAb, long sAh, long sBz, long sBb, long sBh,
    long sCz, long sCb, long sCh, int pstart) {
  int z = blockIdx.z, p = pstart + z, bb = p >> 3, hh = p & 7;
  A  += (size_t)(sAz * z + sAb * bb + sAh * hh);
  BT += (size_t)(sBz * z + sBb * bb + sBh * hh);
  size_t coff = (size_t)(sCz * z + sCb * bb + sCh * hh);

  __shared__ unsigned short Al[128][32];
  __shared__ unsigned short Bl[128][32];
  int t = threadIdx.x;
  int m0 = blockIdx.y * 128, n0 = blockIdx.x * 128;
  int w = t >> 6, l = t & 63;
  int wm = (w >> 1) * 64, wn = (w & 1) * 64;
  int lrow = l & 15, lq = l >> 4;
  floatx4 acc[4][4] = {};

  int srow = t >> 2, scol = (t & 3) * 8;
  const unsigned short* ga = A + (size_t)(m0 + srow) * lda + scol;
  const unsigned short* gb = BT + (size_t)(n0 + srow) * ldb + scol;
  unsigned short* la = &Al[srow][scol];
  unsigned short* lb = &Bl[srow][scol];
  size_t lda64 = (size_t)64 * lda, ldb64 = (size_t)64 * ldb;

  for (int k0 = 0; k0 < K; k0 += 32) {
    GLD_LDS16(ga + k0, la);
    GLD_LDS16(ga + lda64 + k0, la + 64 * 32);
    GLD_LDS16(gb + k0, lb);
    GLD_LDS16(gb + ldb64 + k0, lb + 64 * 32);
    __syncthreads();
    short8 af[4], bf[4];
#pragma unroll
    for (int i = 0; i < 4; i++) af[i] = *(const short8*)&Al[wm + i * 16 + lrow][lq * 8];
#pragma unroll
    for (int j = 0; j < 4; j++) bf[j] = *(const short8*)&Bl[wn + j * 16 + lrow][lq * 8];
#pragma unroll
    for (int i = 0; i < 4; i++)
#pragma unroll
      for (int j = 0; j < 4; j++)
        acc[i][j] = __builtin_amdgcn_mfma_f32_16x16x32_bf16(af[i], bf[j], acc[i][j], 0, 0, 0);
    __syncthreads();
  }
#pragma unroll
  for (int i = 0; i < 4; i++)
#pragma unroll
    for (int j = 0; j < 4; j++)
#pragma unroll
      for (int r = 0; r < 4; r++) {
        int row = m0 + wm + i * 16 + lq * 4 + r;
        int col = n0 + wn + j * 16 + lrow;
        float v = acc[i][j][r];
        if (ADD_BIAS) v += bias[col];
        size_t idx = coff + (size_t)row * ldc + col;
        if (OUT_BF16) ((unsigned short*)Cv)[idx] = f2b(v);
        else          ((float*)Cv)[idx] = v;
      }
}

// ---------------------------------------------------------------------------
// gemm64: 64(M)x128(N) tile variant (for skinny-M GEMMs like attn@v) — gives
// 2x the blocks of gemm128 when M is small. 4 waves: wave = 32x64, 2x4 MFMA.
// ---------------------------------------------------------------------------
template<int OUT_BF16, int ADD_BIAS>
__global__ __launch_bounds__(256) void gemm64(
    const unsigned short* __restrict__ A, const unsigned short* __restrict__ BT,
    void* __restrict__ Cv, const float* __restrict__ bias,
    int K, int lda, int ldb, int ldc,
    long sAz, long sAb, long sAh, long sBz, long sBb, long sBh,
    long sCz, long sCb, long sCh, int pstart) {
  int z = blockIdx.z, p = pstart + z, bb = p >> 3, hh = p & 7;
  A  += (size_t)(sAz * z + sAb * bb + sAh * hh);
  BT += (size_t)(sBz * z + sBb * bb + sBh * hh);
  size_t coff = (size_t)(sCz * z + sCb * bb + sCh * hh);

  __shared__ unsigned short Al[64][32];
  __shared__ unsigned short Bl[128][32];
  int t = threadIdx.x;
  int m0 = blockIdx.y * 64, n0 = blockIdx.x * 128;
  int w = t >> 6, l = t & 63;
  int wm = (w >> 1) * 32, wn = (w & 1) * 64;
  int lrow = l & 15, lq = l >> 4;
  floatx4 acc[2][4] = {};

  int srow = t >> 2, scol = (t & 3) * 8;
  const unsigned short* ga = A + (size_t)(m0 + srow) * lda + scol;
  const unsigned short* gb = BT + (size_t)(n0 + srow) * ldb + scol;
  unsigned short* la = &Al[srow][scol];
  unsigned short* lb = &Bl[srow][scol];
  size_t ldb64 = (size_t)64 * ldb;

  for (int k0 = 0; k0 < K; k0 += 32) {
    GLD_LDS16(ga + k0, la);
    GLD_LDS16(gb + k0, lb);
    GLD_LDS16(gb + ldb64 + k0, lb + 64 * 32);
    __syncthreads();
    short8 af[2], bf[4];
#pragma unroll
    for (int i = 0; i < 2; i++) af[i] = *(const short8*)&Al[wm + i * 16 + lrow][lq * 8];
#pragma unroll
    for (int j = 0; j < 4; j++) bf[j] = *(const short8*)&Bl[wn + j * 16 + lrow][lq * 8];
#pragma unroll
    for (int i = 0; i < 2; i++)
#pragma unroll
      for (int j = 0; j < 4; j++)
        acc[i][j] = __builtin_amdgcn_mfma_f32_16x16x32_bf16(af[i], bf[j], acc[i][j], 0, 0, 0);
    __syncthreads();
  }
#pragma unroll
  for (int i = 0; i < 2; i++)
#pragma unroll
    for (int j = 0; j < 4; j++)
#pragma unroll
      for (int r = 0; r < 4; r++) {
        int row = m0 + wm + i * 16 + lq * 4 + r;
        int col = n0 + wn + j * 16 + lrow;
        float v = acc[i][j][r];
        if (ADD_BIAS) v += bias[col];
        size_t idx = coff + (size_t)row * ldc + col;
        if (OUT_BF16) ((unsigned short*)Cv)[idx] = f2b(v);
        else          ((float*)Cv)[idx] = v;
      }
}

// ---------------------------------------------------------------------------
// logits prep (per 16-pair chunk): qkf fp32 -> qm[z][1024][384]=[hi|lo|hi],
//                                           km[z][1024][384]=[hi|hi|lo]
// (3-term split kept here: logits are the precision-critical dot products)
// ---------------------------------------------------------------------------
__global__ __launch_bounds__(256) void logits_prep(
    const float* __restrict__ qkf, unsigned short* __restrict__ qm,
    unsigned short* __restrict__ km, int pstart) {
  int idx = blockIdx.x * 256 + threadIdx.x;
  int z = blockIdx.y;
  int i = idx >> 5;
  int d4 = (idx & 31) * 4;
  int p = pstart + z, b = p >> 3, h = p & 7;
  const float* row = qkf + ((size_t)(b * 1024 + i)) * 2048 + h * 128;
  ushortx4 hi, lo;

  float4 q = *(const float4*)(row + d4);
  hi[0] = f2b(q.x); lo[0] = f2b(q.x - b2f(hi[0]));
  hi[1] = f2b(q.y); lo[1] = f2b(q.y - b2f(hi[1]));
  hi[2] = f2b(q.z); lo[2] = f2b(q.z - b2f(hi[2]));
  hi[3] = f2b(q.w); lo[3] = f2b(q.w - b2f(hi[3]));
  unsigned short* qr = qm + ((size_t)z * 1024 + i) * 384;
  *(ushortx4*)(qr + d4) = hi;
  *(ushortx4*)(qr + 128 + d4) = lo;
  *(ushortx4*)(qr + 256 + d4) = hi;

  float4 k = *(const float4*)(row + 1024 + d4);
  hi[0] = f2b(k.x); lo[0] = f2b(k.x - b2f(hi[0]));
  hi[1] = f2b(k.y); lo[1] = f2b(k.y - b2f(hi[1]));
  hi[2] = f2b(k.z); lo[2] = f2b(k.z - b2f(hi[2]));
  hi[3] = f2b(k.w); lo[3] = f2b(k.w - b2f(hi[3]));
  unsigned short* kr = km + ((size_t)z * 1024 + i) * 384;
  *(ushortx4*)(kr + d4) = hi;
  *(ushortx4*)(kr + 128 + d4) = hi;
  *(ushortx4*)(kr + 256 + d4) = lo;
}

// ---------------------------------------------------------------------------
// per-row fused: p_m = softmax(s_m row) ; dots = p_m*p_v*SCALE + g_l ;
// attn = softmax(dots) -> bf16 in place over pvb.
// One WAVE per row (16 f32/lane x 64 lanes = 1024 cols), 4 rows/block.
// Pure __shfl_xor reductions: zero LDS, zero __syncthreads.
// ---------------------------------------------------------------------------
__global__ __launch_bounds__(256) void softmax_combine(
    const float* __restrict__ smb, unsigned short* __restrict__ pvb,
    const float* __restrict__ g_l, int pstart) {
  int z = blockIdx.y, p = pstart + z;
  int w = threadIdx.x >> 6, l = threadIdx.x & 63;
  int i = blockIdx.x * 4 + w;
  const float* srow = smb + ((size_t)z * 1024 + i) * 1024;
  unsigned short* vrow = pvb + ((size_t)z * 1024 + i) * 1024;
  const float* grow = g_l + ((size_t)p * 1024 + i) * 1024;

  float4 s[4];
#pragma unroll
  for (int j = 0; j < 4; j++) s[j] = *(const float4*)(srow + j * 256 + l * 4);
  float mx = -3.0e38f;
#pragma unroll
  for (int j = 0; j < 4; j++)
    mx = fmaxf(mx, fmaxf(fmaxf(s[j].x, s[j].y), fmaxf(s[j].z, s[j].w)));
#pragma unroll
  for (int o = 32; o; o >>= 1) mx = fmaxf(mx, __shfl_xor(mx, o));
  float sum = 0.0f;
#pragma unroll
  for (int j = 0; j < 4; j++) {
    s[j].x = __expf(s[j].x - mx); s[j].y = __expf(s[j].y - mx);
    s[j].z = __expf(s[j].z - mx); s[j].w = __expf(s[j].w - mx);
    sum += (s[j].x + s[j].y) + (s[j].z + s[j].w);
  }
#pragma unroll
  for (int o = 32; o; o >>= 1) sum += __shfl_xor(sum, o);
  float inv = 1.0f / sum;

  float4 d[4];
#pragma unroll
  for (int j = 0; j < 4; j++) {
    ushortx4 pv = *(const ushortx4*)(vrow + j * 256 + l * 4);
    float4 g = *(const float4*)(grow + j * 256 + l * 4);
    d[j].x = s[j].x * inv * b2f(pv[0]) * SCALE_F + g.x;
    d[j].y = s[j].y * inv * b2f(pv[1]) * SCALE_F + g.y;
    d[j].z = s[j].z * inv * b2f(pv[2]) * SCALE_F + g.z;
    d[j].w = s[j].w * inv * b2f(pv[3]) * SCALE_F + g.w;
  }
  float mx2 = -3.0e38f;
#pragma unroll
  for (int j = 0; j < 4; j++)
    mx2 = fmaxf(mx2, fmaxf(fmaxf(d[j].x, d[j].y), fmaxf(d[j].z, d[j].w)));
#pragma unroll
  for (int o = 32; o; o >>= 1) mx2 = fmaxf(mx2, __shfl_xor(mx2, o));
  float sum2 = 0.0f;
#pragma unroll
  for (int j = 0; j < 4; j++) {
    d[j].x = __expf(d[j].x - mx2); d[j].y = __expf(d[j].y - mx2);
    d[j].z = __expf(d[j].z - mx2); d[j].w = __expf(d[j].w - mx2);
    sum2 += (d[j].x + d[j].y) + (d[j].z + d[j].w);
  }
#pragma unroll
  for (int o = 32; o; o >>= 1) sum2 += __shfl_xor(sum2, o);
  float inv2 = 1.0f / sum2;

#pragma unroll
  for (int j = 0; j < 4; j++) {
    ushortx4 o4;
    o4[0] = f2b(d[j].x * inv2); o4[1] = f2b(d[j].y * inv2);
    o4[2] = f2b(d[j].z * inv2); o4[3] = f2b(d[j].w * inv2);
    *(ushortx4*)(vrow + j * 256 + l * 4) = o4;
  }
}

// ---------------------------------------------------------------------------
// launch
// ---------------------------------------------------------------------------
extern "C" void kernel_launch(void* const* d_in, const int* in_sizes, int n_in,
                              void* d_out, int out_size, void* d_ws, size_t ws_size,
                              hipStream_t stream) {
  (void)in_sizes; (void)n_in; (void)out_size;
  const float* s_v   = (const float*)d_in[0];
  const float* s_m   = (const float*)d_in[1];
  const float* g_l   = (const float*)d_in[2];
  const float* W_qkv = (const float*)d_in[3];
  const float* W_qk  = (const float*)d_in[4];
  const float* W_out = (const float*)d_in[5];
  const float* b_out = (const float*)d_in[6];
  float* out = (float*)d_out;
  char* ws = (char*)d_ws;

  // Big path: all 64 (b,h)-pairs in one pass. Needs 721,420,288 B of ws
  // (harness fill shows ws = 1 GiB). Fallback: original 4-chunk aliased plan.
  const bool big = (ws_size >= (size_t)721420288ull);

  unsigned short *sv_bf, *qm384, *km384, *wtqkv, *wtout, *qkvb, *vt, *ao,
                 *smhl, *wqk_hl, *pvb;
  float *qkf, *smb;
  if (big) {
    sv_bf  = (unsigned short*)(ws);                 // 16.0M
    wtqkv  = (unsigned short*)(ws + 16777216);      //  6.0M
    wtout  = (unsigned short*)(ws + 23068672);      //  2.0M
    qkvb   = (unsigned short*)(ws + 25165824);      // 48.0M
    qkf    = (float*)         (ws + 75497472);      // 64.0M
    vt     = (unsigned short*)(ws + 142606336);     // 16.0M
    ao     = (unsigned short*)(ws + 159383552);     // 16.0M
    smhl   = (unsigned short*)(ws + 176160768);     // 32.0M
    wqk_hl = (unsigned short*)(ws + 209715200);     //  8.0M
    qm384  = (unsigned short*)(ws + 218103808);     // 48.0M (64 pairs)
    km384  = (unsigned short*)(ws + 268435456);     // 48.0M
    smb    = (float*)         (ws + 318767104);     // 256M
    pvb    = (unsigned short*)(ws + 587202560);     // 128M  -> 721,420,288 total
  } else {
    sv_bf  = (unsigned short*)(ws);              // A: s_v bf16 16M
    qm384  = (unsigned short*)(ws);              // B: alias, 12.6M
    wtqkv  = (unsigned short*)(ws + 16777216);   // A: 6.3M
    km384  = (unsigned short*)(ws + 16777216);   // B: alias, 12.6M
    wtout  = (unsigned short*)(ws + 29360128);   // persistent 2M
    qkvb   = (unsigned short*)(ws + 31457280);   // persistent 48M
    qkf    = (float*)         (ws + 81788928);   // persistent 64M
    vt     = (unsigned short*)(ws + 148897792);  // persistent 16M
    ao     = (unsigned short*)(ws + 165675008);  // persistent 16M
    smhl   = (unsigned short*)(ws + 182452224);  // A: 32M
    smb    = (float*)         (ws + 182452224);  // B: alias, 64M
    wqk_hl = (unsigned short*)(ws + 249561088);  // A: 8M
    pvb    = (unsigned short*)(ws + 249561088);  // B: alias, 32M
  }

  // 1. cast s_v -> bf16
  cast_bf16_kernel<<<dim3(8192), 256, 0, stream>>>(s_v, sv_bf, 8388608);
  // 2-3. weight transposes (bf16)
  transpose_any<0><<<dim3(96, 32, 1), 256, 0, stream>>>(
      W_qkv, wtqkv, 1024, 3072, 3072, 1024, 0, 0, 0, 0, 0);
  transpose_any<0><<<dim3(32, 32, 1), 256, 0, stream>>>(
      W_out, wtout, 1024, 1024, 1024, 1024, 0, 0, 0, 0, 0);
  // 4. split s_m -> [hi|lo]  (8192 x 2048)
  split2_kernel<<<dim3(8192), 256, 0, stream>>>(s_m, smhl);
  // 5. transpose+split W_qk -> [2048][2048] = [hi|hi]
  transpose_split_qk<<<dim3(64, 32, 1), 256, 0, stream>>>(W_qk, wqk_hl);
  // 6. qkv = s_v @ W_qkv  (bf16 MFMA 128-tile)
  gemm128<1, 0><<<dim3(24, 64, 1), 256, 0, stream>>>(
      sv_bf, wtqkv, qkvb, nullptr, 1024, 1024, 1024, 3072,
      0, 0, 0, 0, 0, 0, 0, 0, 0, 0);
  // 7. qk = s_m @ W_qk in 2-term split-bf16 (K=2048), fp32 out
  gemm128<0, 0><<<dim3(16, 64, 1), 256, 0, stream>>>(
      smhl, wqk_hl, qkf, nullptr, 2048, 2048, 2048, 2048,
      0, 0, 0, 0, 0, 0, 0, 0, 0, 0);
  // 8. v^T per (b,h): vt[p][d][j]
  transpose_any<2><<<dim3(4, 32, 64), 256, 0, stream>>>(
      qkvb + 2048, vt, 1024, 128, 3072, 1024,
      (long)1024 * 3072, 128, (long)1048576, 131072, 0);

  if (big) {
    // 9. all 64 (b,h)-pairs in one pass: 4x bigger grids, 14 launches total
    logits_prep<<<dim3(128, 64), 256, 0, stream>>>(qkf, qm384, km384, 0);
    // s_m logits via 3-term split-bf16 (K=384), fp32 out
    gemm128<0, 0><<<dim3(8, 8, 64), 256, 0, stream>>>(
        qm384, km384, smb, nullptr, 384, 384, 384, 1024,
        (long)1024 * 384, 0, 0, (long)1024 * 384, 0, 0,
        (long)1048576, 0, 0, 0);
    // p_v = q_v @ k_v^T (bf16, K=128)
    gemm128<1, 0><<<dim3(8, 8, 64), 256, 0, stream>>>(
        qkvb, qkvb + 1024, pvb, nullptr, 128, 3072, 3072, 1024,
        0, (long)1024 * 3072, 128, 0, (long)1024 * 3072, 128,
        (long)1048576, 0, 0, 0);
    // fused double-softmax + combine -> attn (bf16, in place over pvb)
    softmax_combine<<<dim3(256, 64), 256, 0, stream>>>(smb, pvb, g_l, 0);
    // ao = attn @ v — grid 512 blocks: use the denser 128-tile gemm
    gemm128<1, 0><<<dim3(1, 8, 64), 256, 0, stream>>>(
        pvb, vt, ao, nullptr, 1024, 1024, 1024, 1024,
        (long)1048576, 0, 0, 0, (long)1048576, 131072,
        0, (long)1048576, 128, 0);
  } else {
    // 9. chunks of 16 (b,h)-pairs (original plan)
    for (int c = 0; c < 4; c++) {
      int pstart = c * 16;
      logits_prep<<<dim3(128, 16), 256, 0, stream>>>(qkf, qm384, km384, pstart);
      gemm128<0, 0><<<dim3(8, 8, 16), 256, 0, stream>>>(
          qm384, km384, smb, nullptr, 384, 384, 384, 1024,
          (long)1024 * 384, 0, 0, (long)1024 * 384, 0, 0,
          (long)1048576, 0, 0, pstart);
      gemm128<1, 0><<<dim3(8, 8, 16), 256, 0, stream>>>(
          qkvb, qkvb + 1024, pvb, nullptr, 128, 3072, 3072, 1024,
          0, (long)1024 * 3072, 128, 0, (long)1024 * 3072, 128,
          (long)1048576, 0, 0, pstart);
      softmax_combine<<<dim3(256, 16), 256, 0, stream>>>(smb, pvb, g_l, pstart);
      gemm64<1, 0><<<dim3(1, 16, 16), 256, 0, stream>>>(
          pvb, vt, ao, nullptr, 1024, 1024, 1024, 1024,
          (long)1048576, 0, 0, 0, (long)1048576, 131072,
          0, (long)1048576, 128, pstart);
    }
  }
  // 10. out = ao @ W_out + b_out (fp32 out)
  gemm128<0, 1><<<dim3(8, 64, 1), 256, 0, stream>>>(
      ao, wtout, out, b_out, 1024, 1024, 1024, 1024,
      0, 0, 0, 0, 0, 0, 0, 0, 0, 0);
}